// Round 4
// baseline (744.840 us; speedup 1.0000x reference)
//
#include <hip/hip_runtime.h>
#include <cstdint>

// ---------------------------------------------------------------------------
// PureCorrelation: out = (mask' . relu(Q @ Kp^T)) @ Vp
//   Kp = K W1^T + b1,  Vp = V W2^T + b2,  mask' = mask with col0 true.
// R4: R3 + split-K=2 on the out GEMM (grid 512 -> 1024 blocks, 4/CU) with
// fp32 partials + reduce kernel; converts merged into 2 launches.
// ---------------------------------------------------------------------------

typedef __bf16 bf16x8 __attribute__((ext_vector_type(8)));
typedef float f32x4 __attribute__((ext_vector_type(4)));

__device__ __forceinline__ unsigned short f2bf(float f) {
  unsigned int u = __float_as_uint(f);
  u += 0x7fffu + ((u >> 16) & 1u);
  return (unsigned short)(u >> 16);
}

// async global->LDS, 16B per lane. LDS dest is wave-uniform base + lane*16.
__device__ __forceinline__ void async_load16(const void* g, void* l) {
  __builtin_amdgcn_global_load_lds(
      (const __attribute__((address_space(1))) unsigned int*)(uintptr_t)g,
      (__attribute__((address_space(3))) unsigned int*)(unsigned int)(uintptr_t)l,
      16, 0, 0);
}

// 3 equal-size fp32 arrays -> bf16 in one launch (z selects array)
__global__ void cvt3_f32_bf16(const float* __restrict__ i0, const float* __restrict__ i1,
                              const float* __restrict__ i2,
                              unsigned short* __restrict__ o0, unsigned short* __restrict__ o1,
                              unsigned short* __restrict__ o2, int n4) {
  int i = blockIdx.x * blockDim.x + threadIdx.x;
  if (i >= n4) return;
  const float* in = (blockIdx.y == 0) ? i0 : (blockIdx.y == 1) ? i1 : i2;
  unsigned short* out = (blockIdx.y == 0) ? o0 : (blockIdx.y == 1) ? o1 : o2;
  float4 f = ((const float4*)in)[i];
  ushort4 o;
  o.x = f2bf(f.x); o.y = f2bf(f.y); o.z = f2bf(f.z); o.w = f2bf(f.w);
  ((ushort4*)out)[i] = o;
}

__global__ void cvt2_f32_bf16(const float* __restrict__ i0, const float* __restrict__ i1,
                              unsigned short* __restrict__ o0, unsigned short* __restrict__ o1,
                              int n4) {
  int i = blockIdx.x * blockDim.x + threadIdx.x;
  if (i >= n4) return;
  const float* in = (blockIdx.y == 0) ? i0 : i1;
  unsigned short* out = (blockIdx.y == 0) ? o0 : o1;
  float4 f = ((const float4*)in)[i];
  ushort4 o;
  o.x = f2bf(f.x); o.y = f2bf(f.y); o.z = f2bf(f.z); o.w = f2bf(f.w);
  ((ushort4*)out)[i] = o;
}

// mask int32 [B][S][S] -> bits [B][S][S/32]; column 0 forced true.
__global__ void pack_mask(const int* __restrict__ m, unsigned int* __restrict__ bits) {
  const int lane = threadIdx.x & 63;
  const size_t wid = ((size_t)blockIdx.x * blockDim.x + threadIdx.x) >> 6;
  const size_t base = wid * 256;
  unsigned long long bl[4];
#pragma unroll
  for (int c = 0; c < 4; ++c) {
    size_t e = base + (size_t)c * 64 + lane;
    int col = (int)(e & 4095);  // S = 4096
    bl[c] = __ballot((m[e] != 0) || (col == 0));
  }
  if (lane < 8)
    bits[base / 32 + lane] = (unsigned int)(bl[lane >> 1] >> ((lane & 1) * 32));
}

// out = partial0 + partial1 (split-K reduction), float4-vectorized
__global__ void reduce_split(const float* __restrict__ p, float* __restrict__ out,
                             long long half_elems, int n4) {
  int i = blockIdx.x * blockDim.x + threadIdx.x;
  if (i >= n4) return;
  float4 a = ((const float4*)p)[i];
  float4 b = ((const float4*)(p + half_elems))[i];
  float4 r;
  r.x = a.x + b.x; r.y = a.y + b.y; r.z = a.z + b.z; r.w = a.w + b.w;
  ((float4*)out)[i] = r;
}

// C = A[M,K] @ B[N,K]^T (+ epilogue). Row-major, lda=K, ldb=K, ldc=N.
// EPI: 0 = +bias[n] store bf16 (K proj)
//      1 = +bias[m] store bf16 (V proj, transposed output)
//      2 = bitmask+relu store bf16 (alpha)
//      3 = split-K=2 fp32 partial store (out GEMM): z = ks*4 + batch
template <int EPI>
__global__ void __launch_bounds__(256)
gemm_bt(const unsigned short* __restrict__ A, const unsigned short* __restrict__ B,
        void* __restrict__ Cout, const float* __restrict__ bias,
        const unsigned int* __restrict__ mbits,
        int M, int N, int K,
        long long strA, long long strB, long long strC, long long strM) {
  __shared__ unsigned short sA[128 * 32];
  __shared__ unsigned short sB[128 * 32];

  const int tid  = threadIdx.x;
  const int lane = tid & 63;
  const int wave = tid >> 6;
  const int bz   = blockIdx.z;
  const int tn0  = blockIdx.x * 128;
  const int tm0  = blockIdx.y * 128;

  int bb = bz, kbeg = 0, kend = K;
  if constexpr (EPI == 3) {           // split-K=2: bz = ks*4 + batch
    bb = bz & 3;
    kbeg = (bz >> 2) * (K >> 1);
    kend = kbeg + (K >> 1);
  }

  const unsigned short* Ab = A + (size_t)bb * strA;
  const unsigned short* Bb = B + (size_t)bb * strB;

  const int ldrow = lane >> 2;
  const int lcol  = (lane & 3) * 8;
  const int wm = (wave >> 1) * 64;
  const int wn = (wave & 1) * 64;
  const int lr = lane & 15;
  const int lq = lane >> 4;

  f32x4 acc[4][4] = {};

  for (int k0 = kbeg; k0 < kend; k0 += 32) {
#pragma unroll
    for (int l = 0; l < 2; ++l) {
      const int row = wave * 32 + l * 16;
      async_load16(Ab + (size_t)(tm0 + row + ldrow) * K + (k0 + lcol), &sA[row * 32]);
      async_load16(Bb + (size_t)(tn0 + row + ldrow) * K + (k0 + lcol), &sB[row * 32]);
    }
    __syncthreads();

    bf16x8 af[4], bfr[4];
#pragma unroll
    for (int t = 0; t < 4; ++t) {
      af[t]  = *(const bf16x8*)&sA[(wm + t * 16 + lr) * 32 + lq * 8];
      bfr[t] = *(const bf16x8*)&sB[(wn + t * 16 + lr) * 32 + lq * 8];
    }
#pragma unroll
    for (int mt = 0; mt < 4; ++mt)
#pragma unroll
      for (int nt = 0; nt < 4; ++nt)
        acc[mt][nt] = __builtin_amdgcn_mfma_f32_16x16x32_bf16(af[mt], bfr[nt],
                                                              acc[mt][nt], 0, 0, 0);
    __syncthreads();
  }

  // epilogue: C/D layout col = lane&15, row = (lane>>4)*4 + reg
#pragma unroll
  for (int mt = 0; mt < 4; ++mt) {
#pragma unroll
    for (int r = 0; r < 4; ++r) {
      const int m = tm0 + wm + mt * 16 + lq * 4 + r;
      unsigned long long w64 = 0;
      if constexpr (EPI == 2) {
        w64 = *(const unsigned long long*)&mbits[(size_t)bz * strM +
                                                 (size_t)m * (N >> 5) + ((tn0 + wn) >> 5)];
      }
#pragma unroll
      for (int nt = 0; nt < 4; ++nt) {
        const int n = tn0 + wn + nt * 16 + lr;
        float v = acc[mt][nt][r];
        if constexpr (EPI == 0) {
          v += bias[n];
          ((unsigned short*)Cout)[(size_t)bz * strC + (size_t)m * N + n] = f2bf(v);
        } else if constexpr (EPI == 1) {
          v += bias[m];
          ((unsigned short*)Cout)[(size_t)bz * strC + (size_t)m * N + n] = f2bf(v);
        } else if constexpr (EPI == 2) {
          v = ((w64 >> (nt * 16 + lr)) & 1ull) ? fmaxf(v, 0.f) : 0.f;
          ((unsigned short*)Cout)[(size_t)bz * strC + (size_t)m * N + n] = f2bf(v);
        } else {
          ((float*)Cout)[(size_t)bz * strC + (size_t)m * N + n] = v;
        }
      }
    }
  }
}

extern "C" void kernel_launch(void* const* d_in, const int* in_sizes, int n_in,
                              void* d_out, int out_size, void* d_ws, size_t ws_size,
                              hipStream_t stream) {
  const float* query = (const float*)d_in[0];
  const float* key   = (const float*)d_in[1];
  const float* value = (const float*)d_in[2];
  const int*   mask  = (const int*)d_in[3];
  const float* W1    = (const float*)d_in[4];
  const float* b1    = (const float*)d_in[5];
  const float* W2    = (const float*)d_in[6];
  const float* b2    = (const float*)d_in[7];
  float* out = (float*)d_out;

  constexpr int B = 4, S = 4096, E = 512;
  constexpr long long BSE = (long long)B * S * E;
  constexpr long long SE  = (long long)S * E;
  constexpr long long SS  = (long long)S * S;
  constexpr long long BSS = (long long)B * S * S;
  constexpr long long EE  = (long long)E * E;

  char* ws = (char*)d_ws;
  unsigned short* Qb   = (unsigned short*)ws;  ws += BSE * 2;
  unsigned short* Kb   = (unsigned short*)ws;  ws += BSE * 2;
  unsigned short* Vb   = (unsigned short*)ws;  ws += BSE * 2;
  unsigned short* W1b  = (unsigned short*)ws;  ws += EE * 2;
  unsigned short* W2b  = (unsigned short*)ws;  ws += EE * 2;
  unsigned short* Kp   = (unsigned short*)ws;  ws += BSE * 2;   // [B*S, E]
  unsigned short* Vpt  = (unsigned short*)ws;  ws += BSE * 2;   // [B][E][S]
  unsigned short* alph = (unsigned short*)ws;  ws += BSS * 2;   // [B][S][S]
  unsigned int*   mbit = (unsigned int*)ws;    ws += BSS / 8;   // [B][S][S/32]
  float*          part = (float*)ws;           ws += BSE * 4 * 2; // 2 x [B][S][E] fp32

  // fp32 -> bf16 casts (merged launches)
  cvt3_f32_bf16<<<dim3(BSE / 1024, 3), 256, 0, stream>>>(
      query, key, value, Qb, Kb, Vb, (int)(BSE / 4));
  cvt2_f32_bf16<<<dim3(EE / 1024, 2), 256, 0, stream>>>(
      W1, W2, W1b, W2b, (int)(EE / 4));

  // int32 mask -> bits (col 0 forced true)
  pack_mask<<<dim3((int)(BSS / 1024)), 256, 0, stream>>>(mask, mbit);

  // Kp = Kb @ W1^T + b1   (M=B*S, N=E, K=E)
  gemm_bt<0><<<dim3(E / 128, (B * S) / 128, 1), 256, 0, stream>>>(
      Kb, W1b, Kp, b1, nullptr, B * S, E, E, 0, 0, 0, 0);

  // Vpt[b][f][s] = W2 @ Vb^T + b2   (M=E, N=S, K=E, per batch)
  gemm_bt<1><<<dim3(S / 128, E / 128, B), 256, 0, stream>>>(
      W2b, Vb, Vpt, b2, nullptr, E, S, E, 0, SE, SE, 0);

  // alpha = bitmask-relu(Qb @ Kp^T)   (M=N=S, K=E, per batch)
  gemm_bt<2><<<dim3(S / 128, S / 128, B), 256, 0, stream>>>(
      Qb, Kp, alph, nullptr, mbit, S, S, E, SE, SE, SS, SS / 32);

  // out partials = alpha @ Vpt^T, split-K=2  (M=S, N=E, K=S; z = ks*4+b)
  gemm_bt<3><<<dim3(E / 128, S / 128, 2 * B), 256, 0, stream>>>(
      alph, Vpt, part, nullptr, nullptr, S, E, S, SS, SE, SE, 0);

  // out = part[0] + part[1]
  reduce_split<<<dim3((int)(BSE / 1024)), 256, 0, stream>>>(
      part, out, BSE, (int)(BSE / 4));
}

// Round 5
// 705.884 us; speedup vs baseline: 1.0552x; 1.0552x over previous
//
#include <hip/hip_runtime.h>
#include <cstdint>

// ---------------------------------------------------------------------------
// PureCorrelation: out = (mask' . relu(Q @ Kp^T)) @ Vp
//   Kp = K W1^T + b1,  Vp = V W2^T + b2,  mask' = mask with col0 true.
// R5: R3 (no split-K) with BK=64 K-loop: two m97-pattern BK=32 chunk groups
// staged per barrier pair -> 32 MFMAs between vmcnt(0) drains instead of 16.
// LDS 32 KB, same banking/global_load_lds layout as the verified m97 tile.
// ---------------------------------------------------------------------------

typedef __bf16 bf16x8 __attribute__((ext_vector_type(8)));
typedef float f32x4 __attribute__((ext_vector_type(4)));

__device__ __forceinline__ unsigned short f2bf(float f) {
  unsigned int u = __float_as_uint(f);
  u += 0x7fffu + ((u >> 16) & 1u);
  return (unsigned short)(u >> 16);
}

// async global->LDS, 16B per lane. LDS dest is wave-uniform base + lane*16.
__device__ __forceinline__ void async_load16(const void* g, void* l) {
  __builtin_amdgcn_global_load_lds(
      (const __attribute__((address_space(1))) unsigned int*)(uintptr_t)g,
      (__attribute__((address_space(3))) unsigned int*)(unsigned int)(uintptr_t)l,
      16, 0, 0);
}

// 3 equal-size fp32 arrays -> bf16 in one launch (y selects array)
__global__ void cvt3_f32_bf16(const float* __restrict__ i0, const float* __restrict__ i1,
                              const float* __restrict__ i2,
                              unsigned short* __restrict__ o0, unsigned short* __restrict__ o1,
                              unsigned short* __restrict__ o2, int n4) {
  int i = blockIdx.x * blockDim.x + threadIdx.x;
  if (i >= n4) return;
  const float* in = (blockIdx.y == 0) ? i0 : (blockIdx.y == 1) ? i1 : i2;
  unsigned short* out = (blockIdx.y == 0) ? o0 : (blockIdx.y == 1) ? o1 : o2;
  float4 f = ((const float4*)in)[i];
  ushort4 o;
  o.x = f2bf(f.x); o.y = f2bf(f.y); o.z = f2bf(f.z); o.w = f2bf(f.w);
  ((ushort4*)out)[i] = o;
}

__global__ void cvt2_f32_bf16(const float* __restrict__ i0, const float* __restrict__ i1,
                              unsigned short* __restrict__ o0, unsigned short* __restrict__ o1,
                              int n4) {
  int i = blockIdx.x * blockDim.x + threadIdx.x;
  if (i >= n4) return;
  const float* in = (blockIdx.y == 0) ? i0 : i1;
  unsigned short* out = (blockIdx.y == 0) ? o0 : o1;
  float4 f = ((const float4*)in)[i];
  ushort4 o;
  o.x = f2bf(f.x); o.y = f2bf(f.y); o.z = f2bf(f.z); o.w = f2bf(f.w);
  ((ushort4*)out)[i] = o;
}

// mask int32 [B][S][S] -> bits [B][S][S/32]; column 0 forced true.
__global__ void pack_mask(const int* __restrict__ m, unsigned int* __restrict__ bits) {
  const int lane = threadIdx.x & 63;
  const size_t wid = ((size_t)blockIdx.x * blockDim.x + threadIdx.x) >> 6;
  const size_t base = wid * 256;
  unsigned long long bl[4];
#pragma unroll
  for (int c = 0; c < 4; ++c) {
    size_t e = base + (size_t)c * 64 + lane;
    int col = (int)(e & 4095);  // S = 4096
    bl[c] = __ballot((m[e] != 0) || (col == 0));
  }
  if (lane < 8)
    bits[base / 32 + lane] = (unsigned int)(bl[lane >> 1] >> ((lane & 1) * 32));
}

// C = A[M,K] @ B[N,K]^T (+ epilogue). Row-major, lda=K, ldb=K, ldc=N.
// EPI: 0 = +bias[n] store bf16 (K proj)
//      1 = +bias[m] store bf16 (V proj, transposed output)
//      2 = bitmask+relu store bf16 (alpha)
//      3 = plain store fp32 (final out)
template <int EPI>
__global__ void __launch_bounds__(256)
gemm_bt(const unsigned short* __restrict__ A, const unsigned short* __restrict__ B,
        void* __restrict__ Cout, const float* __restrict__ bias,
        const unsigned int* __restrict__ mbits,
        int M, int N, int K,
        long long strA, long long strB, long long strC, long long strM) {
  __shared__ unsigned short sA[2 * 128 * 32];   // two BK=32 chunk groups, 16 KB
  __shared__ unsigned short sB[2 * 128 * 32];

  const int tid  = threadIdx.x;
  const int lane = tid & 63;
  const int wave = tid >> 6;
  const int bz   = blockIdx.z;
  const int tn0  = blockIdx.x * 128;
  const int tm0  = blockIdx.y * 128;

  const unsigned short* Ab = A + (size_t)bz * strA;
  const unsigned short* Bb = B + (size_t)bz * strB;

  const int ldrow = lane >> 2;        // row within a 16-row wave-load
  const int lcol  = (lane & 3) * 8;   // k-element offset within a 32-chunk
  const int wm = (wave >> 1) * 64;
  const int wn = (wave & 1) * 64;
  const int lr = lane & 15;
  const int lq = lane >> 4;

  f32x4 acc[4][4] = {};

  for (int k0 = 0; k0 < K; k0 += 64) {
    // stage two BK=32 chunk groups (A,B: 128x64 total each) then one drain
#pragma unroll
    for (int g = 0; g < 2; ++g)
#pragma unroll
      for (int l = 0; l < 2; ++l) {
        const int row = wave * 32 + l * 16;  // wave-uniform LDS base row
        async_load16(Ab + (size_t)(tm0 + row + ldrow) * K + (k0 + g * 32 + lcol),
                     &sA[g * 4096 + row * 32]);
        async_load16(Bb + (size_t)(tn0 + row + ldrow) * K + (k0 + g * 32 + lcol),
                     &sB[g * 4096 + row * 32]);
      }
    __syncthreads();

#pragma unroll
    for (int g = 0; g < 2; ++g) {
      bf16x8 af[4], bfr[4];
#pragma unroll
      for (int t = 0; t < 4; ++t) {
        af[t]  = *(const bf16x8*)&sA[g * 4096 + (wm + t * 16 + lr) * 32 + lq * 8];
        bfr[t] = *(const bf16x8*)&sB[g * 4096 + (wn + t * 16 + lr) * 32 + lq * 8];
      }
#pragma unroll
      for (int mt = 0; mt < 4; ++mt)
#pragma unroll
        for (int nt = 0; nt < 4; ++nt)
          acc[mt][nt] = __builtin_amdgcn_mfma_f32_16x16x32_bf16(af[mt], bfr[nt],
                                                                acc[mt][nt], 0, 0, 0);
    }
    __syncthreads();
  }

  // epilogue: C/D layout col = lane&15, row = (lane>>4)*4 + reg
#pragma unroll
  for (int mt = 0; mt < 4; ++mt) {
#pragma unroll
    for (int r = 0; r < 4; ++r) {
      const int m = tm0 + wm + mt * 16 + lq * 4 + r;
      unsigned long long w64 = 0;
      if constexpr (EPI == 2) {
        // one aligned 8B word covers this thread's 64-wide n-window
        w64 = *(const unsigned long long*)&mbits[(size_t)bz * strM +
                                                 (size_t)m * (N >> 5) + ((tn0 + wn) >> 5)];
      }
#pragma unroll
      for (int nt = 0; nt < 4; ++nt) {
        const int n = tn0 + wn + nt * 16 + lr;
        float v = acc[mt][nt][r];
        if constexpr (EPI == 0) {
          v += bias[n];
          ((unsigned short*)Cout)[(size_t)bz * strC + (size_t)m * N + n] = f2bf(v);
        } else if constexpr (EPI == 1) {
          v += bias[m];
          ((unsigned short*)Cout)[(size_t)bz * strC + (size_t)m * N + n] = f2bf(v);
        } else if constexpr (EPI == 2) {
          v = ((w64 >> (nt * 16 + lr)) & 1ull) ? fmaxf(v, 0.f) : 0.f;
          ((unsigned short*)Cout)[(size_t)bz * strC + (size_t)m * N + n] = f2bf(v);
        } else {
          ((float*)Cout)[(size_t)bz * strC + (size_t)m * N + n] = v;
        }
      }
    }
  }
}

extern "C" void kernel_launch(void* const* d_in, const int* in_sizes, int n_in,
                              void* d_out, int out_size, void* d_ws, size_t ws_size,
                              hipStream_t stream) {
  const float* query = (const float*)d_in[0];
  const float* key   = (const float*)d_in[1];
  const float* value = (const float*)d_in[2];
  const int*   mask  = (const int*)d_in[3];
  const float* W1    = (const float*)d_in[4];
  const float* b1    = (const float*)d_in[5];
  const float* W2    = (const float*)d_in[6];
  const float* b2    = (const float*)d_in[7];
  float* out = (float*)d_out;

  constexpr int B = 4, S = 4096, E = 512;
  constexpr long long BSE = (long long)B * S * E;
  constexpr long long SE  = (long long)S * E;
  constexpr long long SS  = (long long)S * S;
  constexpr long long BSS = (long long)B * S * S;
  constexpr long long EE  = (long long)E * E;

  char* ws = (char*)d_ws;
  unsigned short* Qb   = (unsigned short*)ws;  ws += BSE * 2;
  unsigned short* Kb   = (unsigned short*)ws;  ws += BSE * 2;
  unsigned short* Vb   = (unsigned short*)ws;  ws += BSE * 2;
  unsigned short* W1b  = (unsigned short*)ws;  ws += EE * 2;
  unsigned short* W2b  = (unsigned short*)ws;  ws += EE * 2;
  unsigned short* Kp   = (unsigned short*)ws;  ws += BSE * 2;   // [B*S, E]
  unsigned short* Vpt  = (unsigned short*)ws;  ws += BSE * 2;   // [B][E][S]
  unsigned short* alph = (unsigned short*)ws;  ws += BSS * 2;   // [B][S][S]
  unsigned int*   mbit = (unsigned int*)ws;    ws += BSS / 8;   // [B][S][S/32]

  // fp32 -> bf16 casts (merged launches)
  cvt3_f32_bf16<<<dim3(BSE / 1024, 3), 256, 0, stream>>>(
      query, key, value, Qb, Kb, Vb, (int)(BSE / 4));
  cvt2_f32_bf16<<<dim3(EE / 1024, 2), 256, 0, stream>>>(
      W1, W2, W1b, W2b, (int)(EE / 4));

  // int32 mask -> bits (col 0 forced true)
  pack_mask<<<dim3((int)(BSS / 1024)), 256, 0, stream>>>(mask, mbit);

  // Kp = Kb @ W1^T + b1   (M=B*S, N=E, K=E)
  gemm_bt<0><<<dim3(E / 128, (B * S) / 128, 1), 256, 0, stream>>>(
      Kb, W1b, Kp, b1, nullptr, B * S, E, E, 0, 0, 0, 0);

  // Vpt[b][f][s] = W2 @ Vb^T + b2   (M=E, N=S, K=E, per batch)
  gemm_bt<1><<<dim3(S / 128, E / 128, B), 256, 0, stream>>>(
      W2b, Vb, Vpt, b2, nullptr, E, S, E, 0, SE, SE, 0);

  // alpha = bitmask-relu(Qb @ Kp^T)   (M=N=S, K=E, per batch)
  gemm_bt<2><<<dim3(S / 128, S / 128, B), 256, 0, stream>>>(
      Qb, Kp, alph, nullptr, mbit, S, S, E, SE, SE, SS, SS / 32);

  // out = alpha @ Vpt^T   (M=S, N=E, K=S, per batch)
  gemm_bt<3><<<dim3(E / 128, S / 128, B), 256, 0, stream>>>(
      alph, Vpt, out, nullptr, nullptr, S, E, S, SS, SE, SE, 0);
}

// Round 6
// 698.148 us; speedup vs baseline: 1.0669x; 1.0111x over previous
//
#include <hip/hip_runtime.h>
#include <cstdint>

// ---------------------------------------------------------------------------
// PureCorrelation: out = (mask' . relu(Q @ Kp^T)) @ Vp
//   Kp = K W1^T + b1,  Vp = V W2^T + b2,  mask' = mask with col0 true.
// R6: R5 (BK=64 GEMMs, bitmask) + launch merging:
//   prep  = cvt(Q,K,V,W1,W2) + pack_mask in ONE launch (role by blockIdx)
//   proj  = Kp-proj + Vpt-proj in ONE launch (1024 blocks = 4/CU co-resident)
// 4 graph nodes total: prep -> proj -> alpha -> out.
// ---------------------------------------------------------------------------

typedef __bf16 bf16x8 __attribute__((ext_vector_type(8)));
typedef float f32x4 __attribute__((ext_vector_type(4)));

__device__ __forceinline__ unsigned short f2bf(float f) {
  unsigned int u = __float_as_uint(f);
  u += 0x7fffu + ((u >> 16) & 1u);
  return (unsigned short)(u >> 16);
}

// async global->LDS, 16B per lane. LDS dest is wave-uniform base + lane*16.
__device__ __forceinline__ void async_load16(const void* g, void* l) {
  __builtin_amdgcn_global_load_lds(
      (const __attribute__((address_space(1))) unsigned int*)(uintptr_t)g,
      (__attribute__((address_space(3))) unsigned int*)(unsigned int)(uintptr_t)l,
      16, 0, 0);
}

// ---------------------------------------------------------------------------
// prep: blocks [0,24576) cvt Q/K/V; [24576,25088) cvt W1/W2; rest pack mask.
// ---------------------------------------------------------------------------
__global__ void __launch_bounds__(256)
prep(const float* __restrict__ q, const float* __restrict__ k,
     const float* __restrict__ v, const float* __restrict__ w1,
     const float* __restrict__ w2, const int* __restrict__ m,
     unsigned short* __restrict__ qb, unsigned short* __restrict__ kb,
     unsigned short* __restrict__ vb, unsigned short* __restrict__ w1b,
     unsigned short* __restrict__ w2b, unsigned int* __restrict__ bits) {
  const int b = blockIdx.x, tid = threadIdx.x;
  if (b < 24576) {                       // Q/K/V fp32->bf16, 8192 blocks each
    const int which = b >> 13;
    const int idx = (b & 8191) * 256 + tid;
    const float* in = (which == 0) ? q : (which == 1) ? k : v;
    unsigned short* out = (which == 0) ? qb : (which == 1) ? kb : vb;
    float4 f = ((const float4*)in)[idx];
    ushort4 o;
    o.x = f2bf(f.x); o.y = f2bf(f.y); o.z = f2bf(f.z); o.w = f2bf(f.w);
    ((ushort4*)out)[idx] = o;
  } else if (b < 25088) {                // W1/W2 fp32->bf16, 256 blocks each
    const int which = (b - 24576) >> 8;
    const int idx = ((b - 24576) & 255) * 256 + tid;
    const float* in = (which == 0) ? w1 : w2;
    unsigned short* out = (which == 0) ? w1b : w2b;
    float4 f = ((const float4*)in)[idx];
    ushort4 o;
    o.x = f2bf(f.x); o.y = f2bf(f.y); o.z = f2bf(f.z); o.w = f2bf(f.w);
    ((ushort4*)out)[idx] = o;
  } else {                               // mask -> bits (col 0 forced true)
    const int lane = tid & 63;
    const size_t wid = (size_t)(b - 25088) * 4 + (tid >> 6);
    const size_t base = wid * 256;
    unsigned long long bl[4];
#pragma unroll
    for (int c = 0; c < 4; ++c) {
      size_t e = base + (size_t)c * 64 + lane;
      int col = (int)(e & 4095);  // S = 4096
      bl[c] = __ballot((m[e] != 0) || (col == 0));
    }
    if (lane < 8)
      bits[base / 32 + lane] = (unsigned int)(bl[lane >> 1] >> ((lane & 1) * 32));
  }
}

// ---------------------------------------------------------------------------
// proj: both E-projections in one launch. Blocks [0,512): Kp = Kb@W1^T+b1
// (M=16384,N=512). Blocks [512,1024): Vpt[b][f][s] = W2@Vb^T+b2 (M=512,N=4096,
// per batch). K=512, lda=ldb=512, BK=64 m97-pattern staging.
// ---------------------------------------------------------------------------
__global__ void __launch_bounds__(256)
proj(const unsigned short* __restrict__ Kb, const unsigned short* __restrict__ W1b,
     unsigned short* __restrict__ Kp, const float* __restrict__ b1,
     const unsigned short* __restrict__ W2b, const unsigned short* __restrict__ Vb,
     unsigned short* __restrict__ Vpt, const float* __restrict__ b2) {
  constexpr int K = 512;
  constexpr long long SE = 4096LL * 512;
  __shared__ unsigned short sA[2 * 128 * 32];
  __shared__ unsigned short sB[2 * 128 * 32];

  const int L = blockIdx.x;
  const unsigned short *Ab, *Bb;
  unsigned short* C;
  const float* bias;
  int tm0, tn0, N, epi;
  if (L < 512) {                 // Kp projection
    tn0 = (L & 3) * 128; tm0 = (L >> 2) * 128;
    Ab = Kb; Bb = W1b; C = Kp; bias = b1; N = 512; epi = 0;
  } else {                       // Vpt projection
    const int t = L - 512;
    tn0 = (t & 31) * 128; tm0 = ((t >> 5) & 3) * 128;
    const int bz = t >> 7;
    Ab = W2b; Bb = Vb + (size_t)bz * SE; C = Vpt + (size_t)bz * SE;
    bias = b2; N = 4096; epi = 1;
  }

  const int tid = threadIdx.x;
  const int lane = tid & 63, wave = tid >> 6;
  const int ldrow = lane >> 2, lcol = (lane & 3) * 8;
  const int wm = (wave >> 1) * 64, wn = (wave & 1) * 64;
  const int lr = lane & 15, lq = lane >> 4;

  f32x4 acc[4][4] = {};

  for (int k0 = 0; k0 < K; k0 += 64) {
#pragma unroll
    for (int g = 0; g < 2; ++g)
#pragma unroll
      for (int l = 0; l < 2; ++l) {
        const int row = wave * 32 + l * 16;
        async_load16(Ab + (size_t)(tm0 + row + ldrow) * K + (k0 + g * 32 + lcol),
                     &sA[g * 4096 + row * 32]);
        async_load16(Bb + (size_t)(tn0 + row + ldrow) * K + (k0 + g * 32 + lcol),
                     &sB[g * 4096 + row * 32]);
      }
    __syncthreads();
#pragma unroll
    for (int g = 0; g < 2; ++g) {
      bf16x8 af[4], bfr[4];
#pragma unroll
      for (int t = 0; t < 4; ++t) {
        af[t]  = *(const bf16x8*)&sA[g * 4096 + (wm + t * 16 + lr) * 32 + lq * 8];
        bfr[t] = *(const bf16x8*)&sB[g * 4096 + (wn + t * 16 + lr) * 32 + lq * 8];
      }
#pragma unroll
      for (int mt = 0; mt < 4; ++mt)
#pragma unroll
        for (int nt = 0; nt < 4; ++nt)
          acc[mt][nt] = __builtin_amdgcn_mfma_f32_16x16x32_bf16(af[mt], bfr[nt],
                                                                acc[mt][nt], 0, 0, 0);
    }
    __syncthreads();
  }

#pragma unroll
  for (int mt = 0; mt < 4; ++mt)
#pragma unroll
    for (int r = 0; r < 4; ++r) {
      const int mm = tm0 + wm + mt * 16 + lq * 4 + r;
#pragma unroll
      for (int nt = 0; nt < 4; ++nt) {
        const int n = tn0 + wn + nt * 16 + lr;
        float v = acc[mt][nt][r];
        v += (epi == 0) ? bias[n] : bias[mm];
        C[(size_t)mm * N + n] = f2bf(v);
      }
    }
}

// C = A[M,K] @ B[N,K]^T (+ epilogue). Row-major, lda=K, ldb=K, ldc=N.
// EPI: 2 = bitmask+relu store bf16 (alpha); 3 = plain store fp32 (final out)
template <int EPI>
__global__ void __launch_bounds__(256)
gemm_bt(const unsigned short* __restrict__ A, const unsigned short* __restrict__ B,
        void* __restrict__ Cout, const unsigned int* __restrict__ mbits,
        int M, int N, int K,
        long long strA, long long strB, long long strC, long long strM) {
  __shared__ unsigned short sA[2 * 128 * 32];
  __shared__ unsigned short sB[2 * 128 * 32];

  const int tid  = threadIdx.x;
  const int lane = tid & 63;
  const int wave = tid >> 6;
  const int bz   = blockIdx.z;
  const int tn0  = blockIdx.x * 128;
  const int tm0  = blockIdx.y * 128;

  const unsigned short* Ab = A + (size_t)bz * strA;
  const unsigned short* Bb = B + (size_t)bz * strB;

  const int ldrow = lane >> 2;
  const int lcol  = (lane & 3) * 8;
  const int wm = (wave >> 1) * 64;
  const int wn = (wave & 1) * 64;
  const int lr = lane & 15;
  const int lq = lane >> 4;

  f32x4 acc[4][4] = {};

  for (int k0 = 0; k0 < K; k0 += 64) {
#pragma unroll
    for (int g = 0; g < 2; ++g)
#pragma unroll
      for (int l = 0; l < 2; ++l) {
        const int row = wave * 32 + l * 16;
        async_load16(Ab + (size_t)(tm0 + row + ldrow) * K + (k0 + g * 32 + lcol),
                     &sA[g * 4096 + row * 32]);
        async_load16(Bb + (size_t)(tn0 + row + ldrow) * K + (k0 + g * 32 + lcol),
                     &sB[g * 4096 + row * 32]);
      }
    __syncthreads();
#pragma unroll
    for (int g = 0; g < 2; ++g) {
      bf16x8 af[4], bfr[4];
#pragma unroll
      for (int t = 0; t < 4; ++t) {
        af[t]  = *(const bf16x8*)&sA[g * 4096 + (wm + t * 16 + lr) * 32 + lq * 8];
        bfr[t] = *(const bf16x8*)&sB[g * 4096 + (wn + t * 16 + lr) * 32 + lq * 8];
      }
#pragma unroll
      for (int mt = 0; mt < 4; ++mt)
#pragma unroll
        for (int nt = 0; nt < 4; ++nt)
          acc[mt][nt] = __builtin_amdgcn_mfma_f32_16x16x32_bf16(af[mt], bfr[nt],
                                                                acc[mt][nt], 0, 0, 0);
    }
    __syncthreads();
  }

#pragma unroll
  for (int mt = 0; mt < 4; ++mt) {
#pragma unroll
    for (int r = 0; r < 4; ++r) {
      const int m = tm0 + wm + mt * 16 + lq * 4 + r;
      unsigned long long w64 = 0;
      if constexpr (EPI == 2) {
        w64 = *(const unsigned long long*)&mbits[(size_t)bz * strM +
                                                 (size_t)m * (N >> 5) + ((tn0 + wn) >> 5)];
      }
#pragma unroll
      for (int nt = 0; nt < 4; ++nt) {
        const int n = tn0 + wn + nt * 16 + lr;
        float v = acc[mt][nt][r];
        if constexpr (EPI == 2) {
          v = ((w64 >> (nt * 16 + lr)) & 1ull) ? fmaxf(v, 0.f) : 0.f;
          ((unsigned short*)Cout)[(size_t)bz * strC + (size_t)m * N + n] = f2bf(v);
        } else {
          ((float*)Cout)[(size_t)bz * strC + (size_t)m * N + n] = v;
        }
      }
    }
  }
}

extern "C" void kernel_launch(void* const* d_in, const int* in_sizes, int n_in,
                              void* d_out, int out_size, void* d_ws, size_t ws_size,
                              hipStream_t stream) {
  const float* query = (const float*)d_in[0];
  const float* key   = (const float*)d_in[1];
  const float* value = (const float*)d_in[2];
  const int*   mask  = (const int*)d_in[3];
  const float* W1    = (const float*)d_in[4];
  const float* b1    = (const float*)d_in[5];
  const float* W2    = (const float*)d_in[6];
  const float* b2    = (const float*)d_in[7];
  float* out = (float*)d_out;

  constexpr int B = 4, S = 4096, E = 512;
  constexpr long long BSE = (long long)B * S * E;
  constexpr long long SE  = (long long)S * E;
  constexpr long long SS  = (long long)S * S;
  constexpr long long BSS = (long long)B * S * S;
  constexpr long long EE  = (long long)E * E;

  char* ws = (char*)d_ws;
  unsigned short* Qb   = (unsigned short*)ws;  ws += BSE * 2;
  unsigned short* Kb   = (unsigned short*)ws;  ws += BSE * 2;
  unsigned short* Vb   = (unsigned short*)ws;  ws += BSE * 2;
  unsigned short* W1b  = (unsigned short*)ws;  ws += EE * 2;
  unsigned short* W2b  = (unsigned short*)ws;  ws += EE * 2;
  unsigned short* Kp   = (unsigned short*)ws;  ws += BSE * 2;   // [B*S, E]
  unsigned short* Vpt  = (unsigned short*)ws;  ws += BSE * 2;   // [B][E][S]
  unsigned short* alph = (unsigned short*)ws;  ws += BSS * 2;   // [B][S][S]
  unsigned int*   mbit = (unsigned int*)ws;    ws += BSS / 8;   // [B][S][S/32]

  // converts + mask packing, one launch
  prep<<<dim3(24576 + 512 + 65536), 256, 0, stream>>>(
      query, key, value, W1, W2, mask, Qb, Kb, Vb, W1b, W2b, mbit);

  // both projections, one launch (1024 blocks = 4/CU)
  proj<<<dim3(1024), 256, 0, stream>>>(Kb, W1b, Kp, b1, W2b, Vb, Vpt, b2);

  // alpha = bitmask-relu(Qb @ Kp^T)   (M=N=S, K=E, per batch)
  gemm_bt<2><<<dim3(S / 128, S / 128, B), 256, 0, stream>>>(
      Qb, Kp, alph, mbit, S, S, E, SE, SE, SS, SS / 32);

  // out = alpha @ Vpt^T   (M=S, N=E, K=S, per batch)
  gemm_bt<3><<<dim3(E / 128, S / 128, B), 256, 0, stream>>>(
      alph, Vpt, out, nullptr, S, E, S, SS, SE, SE, 0);
}